// Round 7
// baseline (144.283 us; speedup 1.0000x reference)
//
#include <hip/hip_runtime.h>
#include <math.h>

static constexpr int B_ = 32;
static constexpr int RES_ = 50;
#define NF (1.0f/(2.0f*0.05f*0.05f + 1e-8f))   // ~199.9996

typedef _Float16 half8 __attribute__((ext_vector_type(8)));
typedef float f32x4 __attribute__((ext_vector_type(4)));

// ---------------------------------------------------------------------------
// K1: per-batch rank-N update  out[b] = A^T B  via MFMA 16x16x32 f16.
//     A[n,i] = w_n * exp(-(x_i - b_n)^2 nf), B[n,j] = exp(-(y_j - d_n)^2 nf),
//     i,j padded 50->64 (padding rows/cols computed but never stored).
//     Grid 256 = (b:32, kc:8); block = 512 thr = 8 waves; each wave owns
//     1024 points = 32 K-steps of 32, accumulating the full 64x64 tile-set
//     (16 acc tiles). No LDS in main loop, no atomics, no histogram.
//     Fragment mapping (CDNA4 16x16x32): lane&15 -> m (A-row / B-col / D-col);
//     lane>>4 -> k-group of 8. Any consistent k-permutation of A and B is
//     sum-invariant, so only the lane&15 mapping matters (m89-verified for D).
// ---------------------------------------------------------------------------
__global__ void __launch_bounds__(512) k_gemm(const float4* __restrict__ pts,
                                              float* __restrict__ partial) {
    int id = blockIdx.x;
    int kc = id & 7, b = id >> 3;
    int tid = threadIdx.x;
    int w = tid >> 6, lane = tid & 63;
    int kg = lane >> 4, lr = lane & 15;

    // grid coords for this lane's 4 row-tiles (same values serve y/cols)
    float xr[4];
#pragma unroll
    for (int t = 0; t < 4; t++) xr[t] = (float)(t * 16 + lr) * (1.0f / 49.0f);

    // S: exp(-nf t^2) = exp2(-(t*S)^2), S = sqrt(nf * log2(e))
    const float S = sqrtf(NF * 1.44269504f);   // const-folded

    f32x4 acc[4][4];
#pragma unroll
    for (int tm = 0; tm < 4; tm++)
#pragma unroll
        for (int tn = 0; tn < 4; tn++)
#pragma unroll
            for (int r = 0; r < 4; r++) acc[tm][tn][r] = 0.0f;

    // this lane's stream: 8 points per K-step, float4 = 2 points
    const float4* src = pts + ((size_t)b << 15)
                            + (size_t)((kc * 8192 + w * 1024 + kg * 8) >> 1);

    for (int s = 0; s < 32; s++) {
        const float4* q = src + s * 16;
        float4 P0 = q[0], P1 = q[1], P2 = q[2], P3 = q[3];
        float bxs[8] = {P0.x, P0.z, P1.x, P1.z, P2.x, P2.z, P3.x, P3.z};
        float dys[8] = {P0.y, P0.w, P1.y, P1.w, P2.y, P2.w, P3.y, P3.w};

        half8 af[4], bf[4];
#pragma unroll
        for (int e = 0; e < 8; e++) {
            float bx = bxs[e], dy = dys[e];
            float pers = fminf(fabsf(dy - bx), 10.0f);
            float wgt = pers * pers;
#pragma unroll
            for (int t = 0; t < 4; t++) {
                float u = (bx - xr[t]) * S;
                float av = wgt * exp2f(-(u * u));
                float v = (dy - xr[t]) * S;
                float bv = exp2f(-(v * v));
                af[t][e] = (_Float16)av;
                bf[t][e] = (_Float16)bv;
            }
        }
#pragma unroll
        for (int tm = 0; tm < 4; tm++)
#pragma unroll
            for (int tn = 0; tn < 4; tn++)
                acc[tm][tn] = __builtin_amdgcn_mfma_f32_16x16x32_f16(
                    af[tm], bf[tn], acc[tm][tn], 0, 0, 0);
    }

    // cross-wave reduce: LDS [64][65] (stride 65 -> conflict-free ds atomics)
    __shared__ float red[64 * 65];
    for (int t = tid; t < 64 * 65; t += 512) red[t] = 0.0f;
    __syncthreads();

    int rr = kg * 4;                         // D: row = tm*16 + (lane>>4)*4 + r
#pragma unroll
    for (int tm = 0; tm < 4; tm++)
#pragma unroll
        for (int tn = 0; tn < 4; tn++)
#pragma unroll
            for (int r = 0; r < 4; r++)
                atomicAdd(&red[(tm * 16 + rr + r) * 65 + tn * 16 + lr],
                          acc[tm][tn][r]);
    __syncthreads();

    // store rows<50, all 64 cols: partial[(b*8+kc)][50][64]
    float* dst = partial + (size_t)(b * 8 + kc) * 3200;
    for (int t = tid; t < 3200; t += 512) {
        int r = t >> 6, c = t & 63;
        dst[t] = red[r * 65 + c];
    }
}

// ---------------------------------------------------------------------------
// K2: out[b][i][j] = sum_{kc<8} partial[(b*8+kc)][i][j]   (j<50)
// ---------------------------------------------------------------------------
__global__ void __launch_bounds__(256) k_red(const float* __restrict__ partial,
                                             float* __restrict__ out) {
    int b = blockIdx.x;
    const float* p = partial + (size_t)b * 8 * 3200;
    for (int f = threadIdx.x; f < RES_ * RES_; f += 256) {
        int i = f / RES_, j = f - i * RES_;
        int o = i * 64 + j;
        float s = 0.0f;
#pragma unroll
        for (int kc = 0; kc < 8; kc++) s += p[kc * 3200 + o];
        out[(size_t)b * (RES_ * RES_) + f] = s;
    }
}

// ---------------------------------------------------------------------------
extern "C" void kernel_launch(void* const* d_in, const int* in_sizes, int n_in,
                              void* d_out, int out_size, void* d_ws, size_t ws_size,
                              hipStream_t stream) {
    const float4* pts = (const float4*)d_in[0];
    float* ws = (float*)d_ws;
    float* out = (float*)d_out;

    float* partial = ws;                     // 256 * 3200 floats = 3.3 MB

    k_gemm<<<256, 512, 0, stream>>>(pts, partial);
    k_red<<<B_, 256, 0, stream>>>(partial, out);
}

// Round 8
// 105.264 us; speedup vs baseline: 1.3707x; 1.3707x over previous
//
#include <hip/hip_runtime.h>
#include <math.h>

static constexpr int B_ = 32;
static constexpr int RES_ = 50;
#define NF (1.0f/(2.0f*0.05f*0.05f + 1e-8f))   // ~199.9996

typedef _Float16 half8 __attribute__((ext_vector_type(8)));
typedef float f32x4 __attribute__((ext_vector_type(4)));

union H8 { half8 v; unsigned u[4]; };

// ---------------------------------------------------------------------------
// K1: out[b] = A^T B per batch via MFMA 16x16x32 f16 (exact separable form).
//     A[n,i] = w_n exp(-(x_i-b_n)^2 nf), B[n,j] = exp(-(y_j-d_n)^2 nf), 50->64.
//     Grid 512 = (kc:16, b:32), id%8==b%8 (batch's 1 MB of points XCD-local).
//     Block 256 thr = 4 waves; each wave: 1024 points = 32 K-steps; every wave
//     accumulates the full 64x64 tile-set (16 acc tiles, AGPR side).
//     #pragma unroll 1 keeps the K-loop body ~2.3 KB (fits 32 KB L1I).
//     Fragment build: pairs via v_cvt_pkrtz (1 op/pair vs cvt+pack).
// ---------------------------------------------------------------------------
__global__ void __launch_bounds__(256, 2)
k_gemm(const float4* __restrict__ pts, float* __restrict__ partial) {
    int id = blockIdx.x;
    int b = id & 31, kc = id >> 5;
    int tid = threadIdx.x;
    int w = tid >> 6, lane = tid & 63;
    int kg = lane >> 4, lr = lane & 15;

    // exp(-nf t^2) = exp2(-(t*S)^2), S = sqrt(nf*log2(e))  (const-folded)
    const float S = sqrtf(NF * 1.44269504f);
    float xrS[4];
#pragma unroll
    for (int t = 0; t < 4; t++)
        xrS[t] = (float)(t * 16 + lr) * (1.0f / 49.0f) * S;

    f32x4 acc[4][4];
#pragma unroll
    for (int tm = 0; tm < 4; tm++)
#pragma unroll
        for (int tn = 0; tn < 4; tn++)
#pragma unroll
            for (int r = 0; r < 4; r++) acc[tm][tn][r] = 0.0f;

    // float4 units: batch = 32768, kc-chunk = 2048, wave = 512, kg-slice = 4
    const float4* src = pts + ((size_t)b << 15) + (kc << 11) + (w << 9) + (kg << 2);

#pragma unroll 1
    for (int s = 0; s < 32; s++) {
        const float4* q = src + (s << 4);           // advance 32 points
        float4 P0 = q[0], P1 = q[1], P2 = q[2], P3 = q[3];
        float bx[8] = {P0.x, P0.z, P1.x, P1.z, P2.x, P2.z, P3.x, P3.z};
        float dy[8] = {P0.y, P0.w, P1.y, P1.w, P2.y, P2.w, P3.y, P3.w};
        float bS[8], dS[8], wg[8];
#pragma unroll
        for (int e = 0; e < 8; e++) {
            float pers = fminf(fabsf(dy[e] - bx[e]), 10.0f);
            wg[e] = pers * pers;
            bS[e] = bx[e] * S;
            dS[e] = dy[e] * S;
        }
        H8 af[4], bf[4];
#pragma unroll
        for (int t = 0; t < 4; t++) {
#pragma unroll
            for (int pe = 0; pe < 4; pe++) {
                float u0 = bS[2 * pe]     - xrS[t];
                float u1 = bS[2 * pe + 1] - xrS[t];
                float a0 = wg[2 * pe]     * exp2f(-(u0 * u0));
                float a1 = wg[2 * pe + 1] * exp2f(-(u1 * u1));
                af[t].u[pe] = __builtin_bit_cast(unsigned,
                                  __builtin_amdgcn_cvt_pkrtz(a0, a1));
                float v0 = dS[2 * pe]     - xrS[t];
                float v1 = dS[2 * pe + 1] - xrS[t];
                float e0 = exp2f(-(v0 * v0));
                float e1 = exp2f(-(v1 * v1));
                bf[t].u[pe] = __builtin_bit_cast(unsigned,
                                  __builtin_amdgcn_cvt_pkrtz(e0, e1));
            }
        }
#pragma unroll
        for (int tm = 0; tm < 4; tm++)
#pragma unroll
            for (int tn = 0; tn < 4; tn++)
                acc[tm][tn] = __builtin_amdgcn_mfma_f32_16x16x32_f16(
                    af[tm].v, bf[tn].v, acc[tm][tn], 0, 0, 0);
    }

    // cross-wave reduce: LDS [64][68] (stride 68 -> <=2-way bank aliasing)
    __shared__ float red[64 * 68];
    for (int t = tid; t < 64 * 68; t += 256) red[t] = 0.0f;
    __syncthreads();

    int rr = kg * 4;                        // D: row = tm*16 + (lane>>4)*4 + r
#pragma unroll
    for (int tm = 0; tm < 4; tm++)
#pragma unroll
        for (int tn = 0; tn < 4; tn++)
#pragma unroll
            for (int r = 0; r < 4; r++)
                atomicAdd(&red[(tm * 16 + rr + r) * 68 + tn * 16 + lr],
                          acc[tm][tn][r]);
    __syncthreads();

    // store rows<50, 64 cols: partial[(b*16+kc)][50][64]
    float* dst = partial + (size_t)(b * 16 + kc) * 3200;
    for (int t = tid; t < 3200; t += 256)
        dst[t] = red[(t >> 6) * 68 + (t & 63)];
}

// ---------------------------------------------------------------------------
// K2: out[b][i][j] = sum_{kc<16} partial[(b*16+kc)][i][j]   (j<50)
//     Grid 128 = (q:4, b:32): each block does a quarter of one image.
// ---------------------------------------------------------------------------
__global__ void __launch_bounds__(256) k_red(const float* __restrict__ partial,
                                             float* __restrict__ out) {
    int b = blockIdx.x & 31;
    int qq = blockIdx.x >> 5;
    const float* p = partial + (size_t)b * 16 * 3200;
    for (int f = qq * 625 + threadIdx.x; f < (qq + 1) * 625; f += 256) {
        int i = f / RES_, j = f - i * RES_;
        int o = i * 64 + j;
        float s = 0.0f;
#pragma unroll
        for (int kc = 0; kc < 16; kc++) s += p[kc * 3200 + o];
        out[(size_t)b * (RES_ * RES_) + f] = s;
    }
}

// ---------------------------------------------------------------------------
extern "C" void kernel_launch(void* const* d_in, const int* in_sizes, int n_in,
                              void* d_out, int out_size, void* d_ws, size_t ws_size,
                              hipStream_t stream) {
    const float4* pts = (const float4*)d_in[0];
    float* ws = (float*)d_ws;
    float* out = (float*)d_out;

    float* partial = ws;                     // 512 * 3200 floats = 6.6 MB

    k_gemm<<<512, 256, 0, stream>>>(pts, partial);
    k_red<<<128, 256, 0, stream>>>(partial, out);
}

// Round 10
// 80.348 us; speedup vs baseline: 1.7957x; 1.3101x over previous
//
#include <hip/hip_runtime.h>
#include <math.h>

static constexpr int B_ = 32;
static constexpr int RES_ = 50;
#define NF (1.0f/(2.0f*0.05f*0.05f + 1e-8f))   // ~199.9996

typedef _Float16 half8 __attribute__((ext_vector_type(8)));
typedef float    f32x4 __attribute__((ext_vector_type(4)));
typedef unsigned int uint4v __attribute__((ext_vector_type(4)));

// pack two f32 -> one u32 of 2 x f16 (v_cvt_pkrtz_f16_f32), SSA-safe
__device__ __forceinline__ unsigned pk2(float a, float b) {
    return __builtin_bit_cast(unsigned, __builtin_amdgcn_cvt_pkrtz(a, b));
}
__device__ __forceinline__ half8 h8(unsigned a, unsigned b, unsigned c, unsigned d) {
    uint4v u = {a, b, c, d};
    return __builtin_bit_cast(half8, u);
}

#define EX(x)  __builtin_amdgcn_exp2f(x)        // native v_exp_f32 (2^x)
#define SQ(x)  ((x)*(x))

// ---------------------------------------------------------------------------
// K1: out[b] = A^T B per batch via MFMA 16x16x32 f16 (exact separable form).
//     A[n,i] = w_n exp(-(x_i-b_n)^2 nf), B[n,j] = exp(-(y_j-d_n)^2 nf), 50->64.
//     Grid 512 = (kc:16, b:32), id%8==b%8 (batch's points XCD-local).
//     Block 256 = 4 waves; wave owns 1024 points = 32 K-steps of 32.
//     Fragment math all SSA: native exp2, cvt_pkrtz pairs, bit_cast assembly.
// ---------------------------------------------------------------------------
__global__ void __launch_bounds__(256)
k_gemm(const float4* __restrict__ pts, float* __restrict__ partial) {
    int id = blockIdx.x;
    int b = id & 31, kc = id >> 5;
    int tid = threadIdx.x;
    int w = tid >> 6, lane = tid & 63;
    int kg = lane >> 4, lr = lane & 15;

    // exp(-nf t^2) = 2^(-(t*S)^2), S = sqrt(nf*log2(e))
    const float S = sqrtf(NF * 1.44269504f);   // const-folded
    float xr0 = (float)(lr)      * (1.0f / 49.0f) * S;
    float xr1 = (float)(16 + lr) * (1.0f / 49.0f) * S;
    float xr2 = (float)(32 + lr) * (1.0f / 49.0f) * S;
    float xr3 = (float)(48 + lr) * (1.0f / 49.0f) * S;

    f32x4 acc[4][4];
#pragma unroll
    for (int tm = 0; tm < 4; tm++)
#pragma unroll
        for (int tn = 0; tn < 4; tn++)
#pragma unroll
            for (int r = 0; r < 4; r++) acc[tm][tn][r] = 0.0f;

    // float4 units: batch = 32768, kc-chunk = 2048, wave = 512, kg-slice = 4
    const float4* src = pts + ((size_t)b << 15) + (kc << 11) + (w << 9) + (kg << 2);

#pragma unroll 1
    for (int s = 0; s < 32; s++) {
        const float4* q = src + (s << 4);           // advance 32 points
        float4 P0 = q[0], P1 = q[1], P2 = q[2], P3 = q[3];

        // scaled births u*, deaths v*, weights g*
        float u0 = P0.x * S, v0 = P0.y * S;
        float u1 = P0.z * S, v1 = P0.w * S;
        float u2 = P1.x * S, v2 = P1.y * S;
        float u3 = P1.z * S, v3 = P1.w * S;
        float u4 = P2.x * S, v4 = P2.y * S;
        float u5 = P2.z * S, v5 = P2.w * S;
        float u6 = P3.x * S, v6 = P3.y * S;
        float u7 = P3.z * S, v7 = P3.w * S;
        float g0 = SQ(fminf(fabsf(P0.y - P0.x), 10.0f));
        float g1 = SQ(fminf(fabsf(P0.w - P0.z), 10.0f));
        float g2 = SQ(fminf(fabsf(P1.y - P1.x), 10.0f));
        float g3 = SQ(fminf(fabsf(P1.w - P1.z), 10.0f));
        float g4 = SQ(fminf(fabsf(P2.y - P2.x), 10.0f));
        float g5 = SQ(fminf(fabsf(P2.w - P2.z), 10.0f));
        float g6 = SQ(fminf(fabsf(P3.y - P3.x), 10.0f));
        float g7 = SQ(fminf(fabsf(P3.w - P3.z), 10.0f));

#define BUILD(afv, bfv, xrt)                                                  \
        half8 afv = h8(                                                       \
            pk2(g0 * EX(-SQ(u0 - xrt)), g1 * EX(-SQ(u1 - xrt))),              \
            pk2(g2 * EX(-SQ(u2 - xrt)), g3 * EX(-SQ(u3 - xrt))),              \
            pk2(g4 * EX(-SQ(u4 - xrt)), g5 * EX(-SQ(u5 - xrt))),              \
            pk2(g6 * EX(-SQ(u6 - xrt)), g7 * EX(-SQ(u7 - xrt))));             \
        half8 bfv = h8(                                                       \
            pk2(EX(-SQ(v0 - xrt)), EX(-SQ(v1 - xrt))),                        \
            pk2(EX(-SQ(v2 - xrt)), EX(-SQ(v3 - xrt))),                        \
            pk2(EX(-SQ(v4 - xrt)), EX(-SQ(v5 - xrt))),                        \
            pk2(EX(-SQ(v6 - xrt)), EX(-SQ(v7 - xrt))));

        BUILD(af0, bf0, xr0)
        BUILD(af1, bf1, xr1)
        BUILD(af2, bf2, xr2)
        BUILD(af3, bf3, xr3)
#undef BUILD

#define MF(tm, tn) acc[tm][tn] = __builtin_amdgcn_mfma_f32_16x16x32_f16(      \
            af##tm, bf##tn, acc[tm][tn], 0, 0, 0)
        MF(0,0); MF(0,1); MF(0,2); MF(0,3);
        MF(1,0); MF(1,1); MF(1,2); MF(1,3);
        MF(2,0); MF(2,1); MF(2,2); MF(2,3);
        MF(3,0); MF(3,1); MF(3,2); MF(3,3);
#undef MF
    }

    // cross-wave reduce: LDS [64][68] (stride 68 -> <=2-way bank aliasing)
    __shared__ float red[64 * 68];
    for (int t = tid; t < 64 * 68; t += 256) red[t] = 0.0f;
    __syncthreads();

    int rr = kg * 4;                        // D: row = tm*16 + (lane>>4)*4 + r
#pragma unroll
    for (int tm = 0; tm < 4; tm++)
#pragma unroll
        for (int tn = 0; tn < 4; tn++)
#pragma unroll
            for (int r = 0; r < 4; r++)
                atomicAdd(&red[(tm * 16 + rr + r) * 68 + tn * 16 + lr],
                          acc[tm][tn][r]);
    __syncthreads();

    // store rows<50, 64 cols: partial[(b*16+kc)][50][64]
    float* dst = partial + (size_t)(b * 16 + kc) * 3200;
    for (int t = tid; t < 3200; t += 256)
        dst[t] = red[(t >> 6) * 68 + (t & 63)];
}

// ---------------------------------------------------------------------------
// K2: out[b][i][j] = sum_{kc<16} partial[(b*16+kc)][i][j]   (j<50)
//     Grid 128 = (q:4, b:32): each block does a quarter of one image.
// ---------------------------------------------------------------------------
__global__ void __launch_bounds__(256) k_red(const float* __restrict__ partial,
                                             float* __restrict__ out) {
    int b = blockIdx.x & 31;
    int qq = blockIdx.x >> 5;
    const float* p = partial + (size_t)b * 16 * 3200;
    for (int f = qq * 625 + threadIdx.x; f < (qq + 1) * 625; f += 256) {
        int i = f / RES_, j = f - i * RES_;
        int o = i * 64 + j;
        float s = 0.0f;
#pragma unroll
        for (int kc = 0; kc < 16; kc++) s += p[kc * 3200 + o];
        out[(size_t)b * (RES_ * RES_) + f] = s;
    }
}

// ---------------------------------------------------------------------------
extern "C" void kernel_launch(void* const* d_in, const int* in_sizes, int n_in,
                              void* d_out, int out_size, void* d_ws, size_t ws_size,
                              hipStream_t stream) {
    const float4* pts = (const float4*)d_in[0];
    float* ws = (float*)d_ws;
    float* out = (float*)d_out;

    float* partial = ws;                     // 512 * 3200 floats = 6.6 MB

    k_gemm<<<512, 256, 0, stream>>>(pts, partial);
    k_red<<<128, 256, 0, stream>>>(partial, out);
}

// Round 11
// 40.501 us; speedup vs baseline: 3.5625x; 1.9838x over previous
//
#include <hip/hip_runtime.h>
#include <math.h>

static constexpr int B_ = 32;
static constexpr int RES_ = 50;
static constexpr int F_ = 256;              // fine grid
#define NF (1.0f/(2.0f*0.05f*0.05f + 1e-8f))
#define QSCALE 32768.0f                     // weight quantization (2^15)
#define QINV   (1.0f / 32768.0f)

// ---------------------------------------------------------------------------
// K1: bilinear splat into private 64 KB LDS tile of UNSIGNED bins
//     (ds_add_u32 is unconditionally native -- no fp-CAS loop).
//     Grid 512 = (p:4, seg:4, b:32), id%32 == b (XCD-sharded, all blocks
//     co-resident at 2 blocks/CU). 1024 thr; float store converts back.
//     hs_part[p][b][cx][cy], plain stores, no zero-init of hs needed.
// ---------------------------------------------------------------------------
__global__ void __launch_bounds__(1024, 8) k_splat(const float4* __restrict__ pts,
                                                   float* __restrict__ hs) {
    extern __shared__ unsigned tile[];      // 256*64 u32 = 64 KB
    int id  = blockIdx.x;
    int b   = id & 31;
    int seg = (id >> 5) & 3;
    int p   = id >> 7;                      // 0..3

    uint4* t4 = (uint4*)tile;
    for (int t = threadIdx.x; t < 4096; t += 1024)
        t4[t] = make_uint4(0u, 0u, 0u, 0u);
    __syncthreads();

    int ylo = seg << 6;
    const float4* src = pts + ((size_t)b << 15) + ((size_t)p << 13);
    for (int t = threadIdx.x; t < 8192; t += 1024) {
        float4 q = src[t];
#pragma unroll
        for (int h = 0; h < 2; h++) {
            float bx = h ? q.z : q.x;
            float dy = h ? q.w : q.y;
            float pers = fminf(fabsf(dy - bx), 10.0f);
            float wgt = pers * pers * QSCALE;
            float fx = fminf(fmaxf(bx * 255.0f, 0.0f), 255.0f);
            float fy = fminf(fmaxf(dy * 255.0f, 0.0f), 255.0f);
            int ix = (int)fx; if (ix > 254) ix = 254;
            int iy = (int)fy; if (iy > 254) iy = 254;
            float ax = fx - (float)ix;
            float ay = fy - (float)iy;
            int cy0 = iy - ylo;
            float wx0 = wgt * (1.0f - ax), wx1 = wgt * ax;
            int o0 = (ix << 6) + cy0;
            if ((unsigned)cy0 < 64u) {
                float a0 = 1.0f - ay;
                atomicAdd(&tile[o0],      (unsigned)(wx0 * a0 + 0.5f));
                atomicAdd(&tile[o0 + 64], (unsigned)(wx1 * a0 + 0.5f));
            }
            if ((unsigned)(cy0 + 1) < 64u) {
                atomicAdd(&tile[o0 + 1],  (unsigned)(wx0 * ay + 0.5f));
                atomicAdd(&tile[o0 + 65], (unsigned)(wx1 * ay + 0.5f));
            }
        }
    }
    __syncthreads();

    // store: tile[cx][cyL] -> hs[p][b][cx][ylo+cyL], int -> float
    float* dst = hs + (((size_t)p * B_ + b) << 16) + ylo;
    for (int t = threadIdx.x; t < 4096; t += 1024) {
        int cx = t >> 4, c4 = (t & 15) << 2;        // cyL quad
        uint4 iv = t4[t];
        float4 f = make_float4((float)iv.x * QINV, (float)iv.y * QINV,
                               (float)iv.z * QINV, (float)iv.w * QINV);
        *(float4*)(dst + (size_t)cx * F_ + c4) = f;
    }
}

// ---------------------------------------------------------------------------
// K2: T_part[cxq][b][i][cy] = sum_{cx in quarter} G[cx][i] * sum_p hs[p][b][cx][cy]
//     Grid 512 = (cxq:4, cyc:4, b:32), id%8==b%8. Gaussian slice computed
//     in-kernel into 16 KB LDS (padded-slot layout: slot w*16+k -> row
//     i=w*13+k, k<13, i<50; else 0). 4 waves row-split; plain stores.
// ---------------------------------------------------------------------------
__global__ void __launch_bounds__(256, 4) k_conv1(const float* __restrict__ hs,
                                                  float* __restrict__ T) {
    __shared__ float sg[64 * 64];           // 16 KB
    int id  = blockIdx.x;
    int b   = id & 31;
    int r   = id >> 5;
    int cyc = r & 3;
    int cxq = r >> 2;

    for (int t = threadIdx.x; t < 4096; t += 256) {
        int cl = t >> 6, s = t & 63;
        int w = s >> 4, k = s & 15;
        int i = w * 13 + k;
        float v = 0.0f;
        if (k < 13 && i < RES_) {
            float d = (float)i * (1.0f / 49.0f)
                    - (float)((cxq << 6) + cl) * (1.0f / 255.0f);
            v = __expf(-d * d * NF);
        }
        sg[t] = v;
    }
    __syncthreads();

    int tx = threadIdx.x & 63, ty = threadIdx.x >> 6;
    int cy = (cyc << 6) + tx;

    float acc[13];
#pragma unroll
    for (int k = 0; k < 13; k++) acc[k] = 0.0f;

    const float* h0 = hs + ((size_t)b << 16) + ((size_t)(cxq << 6) << 8) + cy;
    const size_t PS = (size_t)B_ << 16;     // part stride
    const float* gq = sg + (ty << 4);
#pragma unroll 4
    for (int c = 0; c < 64; c++) {
        size_t o = (size_t)c << 8;
        float hv = h0[o] + h0[PS + o] + h0[2 * PS + o] + h0[3 * PS + o];
        const float* g = gq + (c << 6);
        float4 g0 = *(const float4*)(g);
        float4 g1 = *(const float4*)(g + 4);
        float4 g2 = *(const float4*)(g + 8);
        float  gc = g[12];
        acc[0]  += g0.x * hv;  acc[1]  += g0.y * hv;
        acc[2]  += g0.z * hv;  acc[3]  += g0.w * hv;
        acc[4]  += g1.x * hv;  acc[5]  += g1.y * hv;
        acc[6]  += g1.z * hv;  acc[7]  += g1.w * hv;
        acc[8]  += g2.x * hv;  acc[9]  += g2.y * hv;
        acc[10] += g2.z * hv;  acc[11] += g2.w * hv;
        acc[12] += gc * hv;
    }

    float* Tp = T + (size_t)cxq * ((size_t)B_ * 52 * F_)
                  + ((size_t)b * 52 + (size_t)ty * 13) * F_ + cy;
#pragma unroll
    for (int k = 0; k < 13; k++) Tp[(size_t)k * F_] = acc[k];
}

// ---------------------------------------------------------------------------
// K3: out[b][i][j] = sum_cy (sum_cxq T_part[cxq][b][i][cy]) * G[cy][j]
//     Grid 128 = (q:4, b:32), id%8==b%8. Gaussian computed inline; T parts
//     summed during LDS staging; 4-wave cy-split + LDS tree reduce.
// ---------------------------------------------------------------------------
__global__ void __launch_bounds__(256) k_conv2(const float* __restrict__ T,
                                               float* __restrict__ out) {
    __shared__ float sT[13 * 256];          // 13 KB, reused as red[4][13][64]
    int b = blockIdx.x & 31;
    int q = blockIdx.x >> 5;

    const size_t TP = (size_t)B_ * 52 * F_;
    const float* Tq = T + ((size_t)b * 52 + (size_t)q * 13) * F_;
    for (int t = threadIdx.x; t < 13 * 256; t += 256)
        sT[t] = Tq[t] + Tq[TP + t] + Tq[2 * TP + t] + Tq[3 * TP + t];
    __syncthreads();

    int j = threadIdx.x & 63;
    int w = threadIdx.x >> 6;
    int jc = j < RES_ ? j : RES_ - 1;
    float xj = (float)jc * (1.0f / 49.0f);

    float acc[13];
#pragma unroll
    for (int k = 0; k < 13; k++) acc[k] = 0.0f;

    int cyb = w * 64;
#pragma unroll 4
    for (int c = 0; c < 64; c++) {
        float d = xj - (float)(cyb + c) * (1.0f / 255.0f);
        float g = __expf(-d * d * NF);
#pragma unroll
        for (int k = 0; k < 13; k++) acc[k] += sT[k * 256 + cyb + c] * g;
    }
    __syncthreads();

#pragma unroll
    for (int k = 0; k < 13; k++) sT[(w * 13 + k) * 64 + j] = acc[k];
    __syncthreads();

    for (int t = threadIdx.x; t < 13 * 64; t += 256) {
        int k = t >> 6, jj = t & 63;
        int i = q * 13 + k;
        if (i < RES_ && jj < RES_) {
            float s = sT[(0 * 13 + k) * 64 + jj] + sT[(1 * 13 + k) * 64 + jj]
                    + sT[(2 * 13 + k) * 64 + jj] + sT[(3 * 13 + k) * 64 + jj];
            out[((size_t)b * RES_ + i) * RES_ + jj] = s;
        }
    }
}

// ---------------------------------------------------------------------------
extern "C" void kernel_launch(void* const* d_in, const int* in_sizes, int n_in,
                              void* d_out, int out_size, void* d_ws, size_t ws_size,
                              hipStream_t stream) {
    const float4* pts = (const float4*)d_in[0];
    float* ws = (float*)d_ws;
    float* out = (float*)d_out;

    float* hs = ws;                           // 4 * 32*256*256 = 8,388,608 floats (33.6 MB)
    float* T  = hs + (size_t)4 * B_ * F_ * F_; // 4 * 32*52*256 = 1,703,936 floats (6.8 MB)
                                              // total ~40.4 MB (ws >= 43.7 MB proven R1)

    k_splat<<<512, 1024, (size_t)F_ * 64 * 4, stream>>>(pts, hs);
    k_conv1<<<512, 256, 0, stream>>>(hs, T);
    k_conv2<<<128, 256, 0, stream>>>(T, out);
}

// Round 12
// 37.238 us; speedup vs baseline: 3.8746x; 1.0876x over previous
//
#include <hip/hip_runtime.h>
#include <math.h>

static constexpr int B_ = 32;
static constexpr int RES_ = 50;
static constexpr int F_ = 256;              // fine grid
#define NF (1.0f/(2.0f*0.05f*0.05f + 1e-8f))
#define QSCALE 2048.0f                      // u16 bin quantization
#define QINV   (1.0f / 2048.0f)
#define EX(x)  __builtin_amdgcn_exp2f(x)    // native v_exp_f32 (2^x)
#define SQ(x)  ((x)*(x))

// ---------------------------------------------------------------------------
// K1: bilinear splat into 64 KB LDS tile of PACKED u16 bins: tile[cx_local]
//     [word], word w = bins (cy=2w lo16, cy=2w+1 hi16). Bilinear touches
//     (cy0, cy0+1): even cy0 -> ONE packed ds_add_u32; odd -> two.
//     Max bin ~14 hits x 2048 = 28K << 65535 (no cross-field carry).
//     Grid 256 = (p:4, xseg:2, b:32), id%32==b (XCD-sharded); full cy range
//     per block, x split in halves -> point visits 2x (was 4x).
//     hs_part[p*2+xseg][b][cx_local:128][word:128] u32, plain stores.
// ---------------------------------------------------------------------------
__global__ void __launch_bounds__(1024, 8) k_splat(const float4* __restrict__ pts,
                                                   unsigned* __restrict__ hs) {
    extern __shared__ unsigned tile[];      // 128*128 u32 = 64 KB
    int id   = blockIdx.x;
    int b    = id & 31;
    int xseg = (id >> 5) & 1;
    int p    = id >> 6;                     // 0..3

    uint4* t4 = (uint4*)tile;
    for (int t = threadIdx.x; t < 4096; t += 1024)
        t4[t] = make_uint4(0u, 0u, 0u, 0u);
    __syncthreads();

    int xlo = xseg << 7;
    const float4* src = pts + ((size_t)b << 15) + ((size_t)p << 13);
    for (int t = threadIdx.x; t < 8192; t += 1024) {
        float4 q = src[t];
#pragma unroll
        for (int h = 0; h < 2; h++) {
            float bx = h ? q.z : q.x;
            float dy = h ? q.w : q.y;
            float pers = fminf(fabsf(dy - bx), 10.0f);
            float wgt = pers * pers;
            float fx = fminf(fmaxf(bx * 255.0f, 0.0f), 255.0f);
            float fy = fminf(fmaxf(dy * 255.0f, 0.0f), 255.0f);
            int ix = (int)fx; if (ix > 254) ix = 254;
            int iy = (int)fy; if (iy > 254) iy = 254;
            float ax = fx - (float)ix;
            float ay = fy - (float)iy;
            float f0 = (1.0f - ay) * QSCALE;
            float f1 = ay * QSCALE;
            float wx0 = wgt * (1.0f - ax), wx1 = wgt * ax;
            int m = iy >> 1, odd = iy & 1;
            int lx0 = ix - xlo;
            if ((unsigned)lx0 < 128u) {
                unsigned v0 = (unsigned)(wx0 * f0 + 0.5f);
                unsigned v1 = (unsigned)(wx0 * f1 + 0.5f);
                unsigned* col = tile + (lx0 << 7);
                if (odd) { atomicAdd(col + m, v0 << 16); atomicAdd(col + m + 1, v1); }
                else     { atomicAdd(col + m, v0 | (v1 << 16)); }
            }
            int lx1 = lx0 + 1;
            if ((unsigned)lx1 < 128u) {
                unsigned v0 = (unsigned)(wx1 * f0 + 0.5f);
                unsigned v1 = (unsigned)(wx1 * f1 + 0.5f);
                unsigned* col = tile + (lx1 << 7);
                if (odd) { atomicAdd(col + m, v0 << 16); atomicAdd(col + m + 1, v1); }
                else     { atomicAdd(col + m, v0 | (v1 << 16)); }
            }
        }
    }
    __syncthreads();

    uint4* d4 = (uint4*)(hs + (((size_t)(p * 2 + xseg) * B_ + b) << 14));
    for (int t = threadIdx.x; t < 4096; t += 1024) d4[t] = t4[t];
}

// ---------------------------------------------------------------------------
// K2: T_part[cxq][b][i][cy] = sum_{cx in quarter} G[cx][i] *
//                             (sum_p unpack(hs[p*2+xseg][b][cx_local][cy]))
//     Grid 512 = (cxq:4, cyc:4, b:32), id%8==b%8. Gaussian slice in 16 KB LDS
//     (slot layout: w*16+k -> row i=w*13+k, k<13, i<50; else 0). Thread tx
//     owns cy = cyc*64+tx -> word cy>>1, half (tx&1); 4 parts summed as ints,
//     one cvt+mul. 4 waves row-split; plain stores; rows 50,51 zeros.
// ---------------------------------------------------------------------------
__global__ void __launch_bounds__(256, 4) k_conv1(const unsigned* __restrict__ hs,
                                                  float* __restrict__ T) {
    __shared__ float sg[64 * 64];           // 16 KB
    int id  = blockIdx.x;
    int b   = id & 31;
    int r   = id >> 5;
    int cyc = r & 3;
    int cxq = r >> 2;

    const float S2 = sqrtf(NF * 1.44269504f);   // const-folded
    for (int t = threadIdx.x; t < 4096; t += 256) {
        int cl = t >> 6, s = t & 63;
        int w = s >> 4, k = s & 15;
        int i = w * 13 + k;
        float v = 0.0f;
        if (k < 13 && i < RES_) {
            float d = ((float)i * (1.0f / 49.0f)
                     - (float)((cxq << 6) + cl) * (1.0f / 255.0f)) * S2;
            v = EX(-SQ(d));
        }
        sg[t] = v;
    }
    __syncthreads();

    int tx = threadIdx.x & 63, ty = threadIdx.x >> 6;
    int cy = (cyc << 6) + tx;
    int sh = (tx & 1) << 4;

    float acc[13];
#pragma unroll
    for (int k = 0; k < 13; k++) acc[k] = 0.0f;

    int xseg = cxq >> 1;
    const unsigned* h0 = hs + (((size_t)xseg * B_ + b) << 14)
                            + ((size_t)((cxq & 1) << 6) << 7)
                            + (cyc << 5) + (tx >> 1);
    const size_t PS = (size_t)(2 * B_) << 14;   // p-part stride (u32)
    const float* gq = sg + (ty << 4);
#pragma unroll 4
    for (int c = 0; c < 64; c++) {
        size_t o = (size_t)c << 7;
        unsigned s0 = h0[o], s1 = h0[PS + o], s2 = h0[2 * PS + o], s3 = h0[3 * PS + o];
        unsigned u = ((s0 >> sh) & 0xffffu) + ((s1 >> sh) & 0xffffu)
                   + ((s2 >> sh) & 0xffffu) + ((s3 >> sh) & 0xffffu);
        float hv = (float)u * QINV;
        const float* g = gq + (c << 6);
        float4 g0 = *(const float4*)(g);
        float4 g1 = *(const float4*)(g + 4);
        float4 g2 = *(const float4*)(g + 8);
        float  gc = g[12];
        acc[0]  += g0.x * hv;  acc[1]  += g0.y * hv;
        acc[2]  += g0.z * hv;  acc[3]  += g0.w * hv;
        acc[4]  += g1.x * hv;  acc[5]  += g1.y * hv;
        acc[6]  += g1.z * hv;  acc[7]  += g1.w * hv;
        acc[8]  += g2.x * hv;  acc[9]  += g2.y * hv;
        acc[10] += g2.z * hv;  acc[11] += g2.w * hv;
        acc[12] += gc * hv;
    }

    float* Tp = T + (size_t)cxq * ((size_t)B_ * 52 * F_)
                  + ((size_t)b * 52 + (size_t)ty * 13) * F_ + cy;
#pragma unroll
    for (int k = 0; k < 13; k++) Tp[(size_t)k * F_] = acc[k];
}

// ---------------------------------------------------------------------------
// K3: out[b][i][j] = sum_cy (sum_cxq T_part[cxq][b][i][cy]) * G[cy][j]
//     Grid 128 = (q:4, b:32), id%8==b%8. Gaussian inline (native exp2);
//     T parts summed during LDS staging; 4-wave cy-split + LDS tree reduce.
// ---------------------------------------------------------------------------
__global__ void __launch_bounds__(256) k_conv2(const float* __restrict__ T,
                                               float* __restrict__ out) {
    __shared__ float sT[13 * 256];          // 13 KB, reused as red[4][13][64]
    int b = blockIdx.x & 31;
    int q = blockIdx.x >> 5;

    const size_t TP = (size_t)B_ * 52 * F_;
    const float* Tq = T + ((size_t)b * 52 + (size_t)q * 13) * F_;
    for (int t = threadIdx.x; t < 13 * 256; t += 256)
        sT[t] = Tq[t] + Tq[TP + t] + Tq[2 * TP + t] + Tq[3 * TP + t];
    __syncthreads();

    int j = threadIdx.x & 63;
    int w = threadIdx.x >> 6;
    int jc = j < RES_ ? j : RES_ - 1;
    const float S2 = sqrtf(NF * 1.44269504f);
    float xjS = (float)jc * (1.0f / 49.0f) * S2;

    float acc[13];
#pragma unroll
    for (int k = 0; k < 13; k++) acc[k] = 0.0f;

    int cyb = w * 64;
#pragma unroll 4
    for (int c = 0; c < 64; c++) {
        float d = xjS - (float)(cyb + c) * (1.0f / 255.0f) * S2;
        float g = EX(-SQ(d));
#pragma unroll
        for (int k = 0; k < 13; k++) acc[k] += sT[k * 256 + cyb + c] * g;
    }
    __syncthreads();

#pragma unroll
    for (int k = 0; k < 13; k++) sT[(w * 13 + k) * 64 + j] = acc[k];
    __syncthreads();

    for (int t = threadIdx.x; t < 13 * 64; t += 256) {
        int k = t >> 6, jj = t & 63;
        int i = q * 13 + k;
        if (i < RES_ && jj < RES_) {
            float s = sT[(0 * 13 + k) * 64 + jj] + sT[(1 * 13 + k) * 64 + jj]
                    + sT[(2 * 13 + k) * 64 + jj] + sT[(3 * 13 + k) * 64 + jj];
            out[((size_t)b * RES_ + i) * RES_ + jj] = s;
        }
    }
}

// ---------------------------------------------------------------------------
extern "C" void kernel_launch(void* const* d_in, const int* in_sizes, int n_in,
                              void* d_out, int out_size, void* d_ws, size_t ws_size,
                              hipStream_t stream) {
    const float4* pts = (const float4*)d_in[0];
    unsigned* hs = (unsigned*)d_ws;          // 8*32*16384 u32 = 16.8 MB
    float* T = (float*)d_ws + (size_t)8 * B_ * 16384;  // 4*32*52*256 f32 = 6.8 MB
    float* out = (float*)d_out;              // total ~23.6 MB (ws >= 43.7 MB proven)

    k_splat<<<256, 1024, 65536, stream>>>(pts, hs);
    k_conv1<<<512, 256, 0, stream>>>(hs, T);
    k_conv2<<<128, 256, 0, stream>>>(T, out);
}

// Round 13
// 35.348 us; speedup vs baseline: 4.0818x; 1.0535x over previous
//
#include <hip/hip_runtime.h>
#include <math.h>

static constexpr int B_ = 32;
static constexpr int RES_ = 50;
static constexpr int F_ = 256;              // fine grid
#define NF (1.0f/(2.0f*0.05f*0.05f + 1e-8f))
#define QSCALE 2048.0f                      // u16 bin quantization
#define QINV   (1.0f / 2048.0f)
#define EX(x)  __builtin_amdgcn_exp2f(x)    // native v_exp_f32 (2^x)
#define SQ(x)  ((x)*(x))

// ---------------------------------------------------------------------------
// K1: splat, NN in x / bilinear in y, into 64 KB LDS tile of PACKED u16 bins:
//     tile[cx_local][word], word w holds cy=2w (lo16) and cy=2w+1 (hi16).
//     Even iy -> ONE packed ds_add_u32; odd -> two. Avg 1.5 lane-atomics/pt
//     (divergent-address LDS atomics serialize per lane -- the measured cost
//     driver; R10->R11 fp->int delta and R11->R12 flatness pin this model).
//     Grid 256 = (p:4, xseg:2, b:32), id%32==b (XCD-sharded; 2 blocks/CU).
//     hs_part[p*2+xseg][b][cx_local:128][word:128] u32, plain stores.
// ---------------------------------------------------------------------------
__global__ void __launch_bounds__(1024, 8) k_splat(const float4* __restrict__ pts,
                                                   unsigned* __restrict__ hs) {
    extern __shared__ unsigned tile[];      // 128*128 u32 = 64 KB
    int id   = blockIdx.x;
    int b    = id & 31;
    int xseg = (id >> 5) & 1;
    int p    = id >> 6;                     // 0..3

    uint4* t4 = (uint4*)tile;
    for (int t = threadIdx.x; t < 4096; t += 1024)
        t4[t] = make_uint4(0u, 0u, 0u, 0u);
    __syncthreads();

    int xlo = xseg << 7;
    const float4* src = pts + ((size_t)b << 15) + ((size_t)p << 13);
    for (int t = threadIdx.x; t < 8192; t += 1024) {
        float4 q = src[t];
#pragma unroll
        for (int h = 0; h < 2; h++) {
            float bx = h ? q.z : q.x;
            float dy = h ? q.w : q.y;
            float pers = fminf(fabsf(dy - bx), 10.0f);
            float wgt = pers * pers * QSCALE;
            // nearest x bin
            float fx = fminf(fmaxf(bx * 255.0f + 0.5f, 0.0f), 255.0f);
            int ix = (int)fx;               // 0..255
            // bilinear y
            float fy = fminf(fmaxf(dy * 255.0f, 0.0f), 255.0f);
            int iy = (int)fy; if (iy > 254) iy = 254;
            float ay = fy - (float)iy;
            float v1f = wgt * ay;
            unsigned v0 = (unsigned)(wgt - v1f + 0.5f);
            unsigned v1 = (unsigned)(v1f + 0.5f);
            int lx = ix - xlo;
            if ((unsigned)lx < 128u) {
                unsigned* col = tile + (lx << 7);
                int w0 = iy >> 1, odd = iy & 1;
                unsigned first = odd ? (v0 << 16) : (v0 | (v1 << 16));
                atomicAdd(col + w0, first);
                if (odd) atomicAdd(col + w0 + 1, v1);
            }
        }
    }
    __syncthreads();

    uint4* d4 = (uint4*)(hs + (((size_t)(p * 2 + xseg) * B_ + b) << 14));
    for (int t = threadIdx.x; t < 4096; t += 1024) d4[t] = t4[t];
}

// ---------------------------------------------------------------------------
// K2: T_part[cxq][b][i][cy] = sum_{cx in quarter} G[cx][i] *
//                             (sum_p hs_u16[p*2+xseg][b][cx][cy])
//     hs viewed as u16[part][b][cx:128][cy:256] (contiguous). Direct ushort
//     loads, 3 int adds, one cvt+mul per c-iter. Gaussian slice in 16 KB LDS
//     (slot layout: w*16+k -> row i=w*13+k, k<13, i<50; else 0).
//     Grid 512 = (cxq:4, cyc:4, b:32), id%8==b%8. 4 waves row-split.
// ---------------------------------------------------------------------------
__global__ void __launch_bounds__(256, 4) k_conv1(const unsigned short* __restrict__ hs16,
                                                  float* __restrict__ T) {
    __shared__ float sg[64 * 64];           // 16 KB
    int id  = blockIdx.x;
    int b   = id & 31;
    int r   = id >> 5;
    int cyc = r & 3;
    int cxq = r >> 2;

    const float S2 = sqrtf(NF * 1.44269504f);   // const-folded
    for (int t = threadIdx.x; t < 4096; t += 256) {
        int cl = t >> 6, s = t & 63;
        int w = s >> 4, k = s & 15;
        int i = w * 13 + k;
        float v = 0.0f;
        if (k < 13 && i < RES_) {
            float d = ((float)i * (1.0f / 49.0f)
                     - (float)((cxq << 6) + cl) * (1.0f / 255.0f)) * S2;
            v = EX(-SQ(d));
        }
        sg[t] = v;
    }
    __syncthreads();

    int tx = threadIdx.x & 63, ty = threadIdx.x >> 6;
    int cy = (cyc << 6) + tx;

    float acc[13];
#pragma unroll
    for (int k = 0; k < 13; k++) acc[k] = 0.0f;

    int xseg = cxq >> 1;
    // u16 units: part tile = 32768, cx stride = 256
    const unsigned short* h0 = hs16 + (((size_t)xseg * B_ + b) << 15)
                                    + ((size_t)((cxq & 1) << 6) << 8) + cy;
    const size_t PS = (size_t)(2 * B_) << 15;   // p-part stride (u16)
    const float* gq = sg + (ty << 4);
#pragma unroll 4
    for (int c = 0; c < 64; c++) {
        size_t o = (size_t)c << 8;
        unsigned u = (unsigned)h0[o] + (unsigned)h0[PS + o]
                   + (unsigned)h0[2 * PS + o] + (unsigned)h0[3 * PS + o];
        float hv = (float)u * QINV;
        const float* g = gq + (c << 6);
        float4 g0 = *(const float4*)(g);
        float4 g1 = *(const float4*)(g + 4);
        float4 g2 = *(const float4*)(g + 8);
        float  gc = g[12];
        acc[0]  += g0.x * hv;  acc[1]  += g0.y * hv;
        acc[2]  += g0.z * hv;  acc[3]  += g0.w * hv;
        acc[4]  += g1.x * hv;  acc[5]  += g1.y * hv;
        acc[6]  += g1.z * hv;  acc[7]  += g1.w * hv;
        acc[8]  += g2.x * hv;  acc[9]  += g2.y * hv;
        acc[10] += g2.z * hv;  acc[11] += g2.w * hv;
        acc[12] += gc * hv;
    }

    float* Tp = T + (size_t)cxq * ((size_t)B_ * 52 * F_)
                  + ((size_t)b * 52 + (size_t)ty * 13) * F_ + cy;
#pragma unroll
    for (int k = 0; k < 13; k++) Tp[(size_t)k * F_] = acc[k];
}

// ---------------------------------------------------------------------------
// K3: out[b][i][j] = sum_cy (sum_cxq T_part[cxq][b][i][cy]) * G[cy][j]
//     Grid 128 = (q:4, b:32), id%8==b%8. Gaussian inline (native exp2);
//     T parts summed during LDS staging; 4-wave cy-split + LDS tree reduce.
// ---------------------------------------------------------------------------
__global__ void __launch_bounds__(256) k_conv2(const float* __restrict__ T,
                                               float* __restrict__ out) {
    __shared__ float sT[13 * 256];          // 13 KB, reused as red[4][13][64]
    int b = blockIdx.x & 31;
    int q = blockIdx.x >> 5;

    const size_t TP = (size_t)B_ * 52 * F_;
    const float* Tq = T + ((size_t)b * 52 + (size_t)q * 13) * F_;
    for (int t = threadIdx.x; t < 13 * 256; t += 256)
        sT[t] = Tq[t] + Tq[TP + t] + Tq[2 * TP + t] + Tq[3 * TP + t];
    __syncthreads();

    int j = threadIdx.x & 63;
    int w = threadIdx.x >> 6;
    int jc = j < RES_ ? j : RES_ - 1;
    const float S2 = sqrtf(NF * 1.44269504f);
    float xjS = (float)jc * (1.0f / 49.0f) * S2;

    float acc[13];
#pragma unroll
    for (int k = 0; k < 13; k++) acc[k] = 0.0f;

    int cyb = w * 64;
#pragma unroll 4
    for (int c = 0; c < 64; c++) {
        float d = xjS - (float)(cyb + c) * (1.0f / 255.0f) * S2;
        float g = EX(-SQ(d));
#pragma unroll
        for (int k = 0; k < 13; k++) acc[k] += sT[k * 256 + cyb + c] * g;
    }
    __syncthreads();

#pragma unroll
    for (int k = 0; k < 13; k++) sT[(w * 13 + k) * 64 + j] = acc[k];
    __syncthreads();

    for (int t = threadIdx.x; t < 13 * 64; t += 256) {
        int k = t >> 6, jj = t & 63;
        int i = q * 13 + k;
        if (i < RES_ && jj < RES_) {
            float s = sT[(0 * 13 + k) * 64 + jj] + sT[(1 * 13 + k) * 64 + jj]
                    + sT[(2 * 13 + k) * 64 + jj] + sT[(3 * 13 + k) * 64 + jj];
            out[((size_t)b * RES_ + i) * RES_ + jj] = s;
        }
    }
}

// ---------------------------------------------------------------------------
extern "C" void kernel_launch(void* const* d_in, const int* in_sizes, int n_in,
                              void* d_out, int out_size, void* d_ws, size_t ws_size,
                              hipStream_t stream) {
    const float4* pts = (const float4*)d_in[0];
    unsigned* hs = (unsigned*)d_ws;          // 8*32*16384 u32 = 16.8 MB
    float* T = (float*)d_ws + (size_t)8 * B_ * 16384;  // 4*32*52*256 f32 = 6.8 MB
    float* out = (float*)d_out;              // total ~23.6 MB (ws >= 43.7 MB proven)

    k_splat<<<256, 1024, 65536, stream>>>(pts, hs);
    k_conv1<<<512, 256, 0, stream>>>((const unsigned short*)hs, T);
    k_conv2<<<128, 256, 0, stream>>>(T, out);
}